// Round 1
// 14474.788 us; speedup vs baseline: 1.1490x; 1.1490x over previous
//
#include <hip/hip_runtime.h>
#include <hip/hip_bf16.h>

#define B_   128
#define T_   512
#define D_   512
#define U_   1024
#define O_   512
#define K_   1536      // D + U
#define G4U_ 4096
#define NBLK 128
#define APITCH 1544    // LDS A-row pitch in shorts (dword stride 772 ≡ 4 mod 32)

typedef __attribute__((ext_vector_type(8))) short short8;
typedef __attribute__((ext_vector_type(4))) float f32x4;
typedef __attribute__((ext_vector_type(4))) int int4v;

__device__ __align__(16) unsigned short g_xbf[(size_t)B_ * T_ * D_];   // x bf16 [b][t][d]
__device__ __align__(16) unsigned short g_Wt[(size_t)G4U_ * K_];       // W^T gate-grouped [cg][k]
__device__ __align__(16) unsigned short g_Wdt[(size_t)O_ * U_];        // Wd^T [o][u]
// h history: slot t holds h_t (slot 0 = h0). Unique slot per step -> consumers may use
// PLAIN CACHED loads: each line is written once (volatile write-through to MALL) and
// first touched by any consumer only after the producer's flag. Same-XCD consumers
// share L2 fills. 513*128*1024*2B = 134.5 MB.
__device__ __align__(16) unsigned short g_hall[(size_t)(T_ + 1) * B_ * U_];
__device__ unsigned int g_flag[NBLK * 32];   // per-block progress, one 128B line each

__device__ __forceinline__ unsigned short f2b(float f) {
  unsigned u = __float_as_uint(f);
  u += 0x7fffu + ((u >> 16) & 1u);   // RNE
  return (unsigned short)(u >> 16);
}

__global__ void prep_kernel(const float* __restrict__ x, const float* __restrict__ h0,
                            const float* __restrict__ kern, const float* __restrict__ rkern,
                            const float* __restrict__ Wd) {
  size_t tid = (size_t)blockIdx.x * blockDim.x + threadIdx.x;
  size_t np  = (size_t)gridDim.x * blockDim.x;
  if (tid < NBLK * 32) g_flag[tid] = 0u;

  const size_t nx8 = (size_t)B_ * T_ * D_ / 8;
  const float4* xv = (const float4*)x;
  for (size_t i = tid; i < nx8; i += np) {
    float4 v0 = xv[2 * i], v1 = xv[2 * i + 1];
    unsigned short tmp[8];
    tmp[0] = f2b(v0.x); tmp[1] = f2b(v0.y); tmp[2] = f2b(v0.z); tmp[3] = f2b(v0.w);
    tmp[4] = f2b(v1.x); tmp[5] = f2b(v1.y); tmp[6] = f2b(v1.z); tmp[7] = f2b(v1.w);
    *(int4*)&g_xbf[i * 8] = *(const int4*)tmp;
  }

  // W layout (verified r1/r2): row cg = (u>>4)*64 + gate*16 + (u&15), k contiguous
  const size_t nw = (size_t)G4U_ * (K_ / 8);
  for (size_t i = tid; i < nw; i += np) {
    size_t cg = i / (K_ / 8);
    int kb = (int)(i % (K_ / 8)) * 8;
    int c = (int)(cg >> 6), g = (int)((cg >> 4) & 3), j = (int)(cg & 15);
    int n = g * 1024 + (c << 4) + j;
    unsigned short tmp[8];
#pragma unroll
    for (int q = 0; q < 8; ++q) {
      int k = kb + q;
      float v = (k < 512) ? kern[(size_t)k * G4U_ + n] : rkern[(size_t)(k - 512) * G4U_ + n];
      tmp[q] = f2b(v);
    }
    *(int4*)&g_Wt[cg * K_ + kb] = *(const int4*)tmp;
  }

  const size_t nd = (size_t)O_ * (U_ / 8);
  for (size_t i = tid; i < nd; i += np) {
    int o  = (int)(i >> 7);
    int ub = (int)(i & 127) * 8;
    unsigned short tmp[8];
#pragma unroll
    for (int q = 0; q < 8; ++q) tmp[q] = f2b(Wd[(size_t)(ub + q) * O_ + o]);
    *(int4*)&g_Wdt[(size_t)o * U_ + ub] = *(const int4*)tmp;
  }

  const size_t nh = (size_t)B_ * U_;
  for (size_t i = tid; i < nh; i += np) g_hall[i] = f2b(h0[i]);  // slot 0 = h0
}

// 128 persistent blocks x 256 threads. Block b: rows m0=(b>>5)*32, u0=(b&31)*32.
// Sync is DISTRIBUTED per m-group (32 blocks sharing rows m0..m0+32): producer sets
// its flag after the vmcnt-draining __syncthreads (h stores at MALL); consumers'
// first 32 lanes poll their 32 producers directly. No central gather/release.
// out[t-1] = h_t @ Wd is computed from the LDS-staged h_t (zero global h reads).
__global__ __launch_bounds__(256, 1) void lstm_kernel(const float* __restrict__ c0,
                                                      const float* __restrict__ bias,
                                                      const float* __restrict__ bd,
                                                      float* __restrict__ out) {
  const int b    = blockIdx.x;
  const int tid  = threadIdx.x;
  const int w    = tid >> 6;
  const int lane = tid & 63;
  const int rg   = lane >> 4;
  const int fr   = lane & 15;
  const int fk   = rg * 8;

  const int m0   = (b >> 5) * 32;
  const int ugrp = b & 31;
  const int u0   = ugrp * 32;
  const int rt   = w >> 1, us = w & 1;
  const int mw   = m0 + rt * 16;
  const int uw   = u0 + us * 16;
  const int cg16 = uw >> 4;

  __shared__ __align__(16) unsigned short Ast[32 * APITCH];
  __shared__ float po[4][16][20];

  const unsigned short* wb[4];
#pragma unroll
  for (int g = 0; g < 4; ++g)
    wb[g] = &g_Wt[(size_t)(cg16 * 64 + g * 16 + fr) * K_ + fk];

  const int crow = mw + rg * 4;
  f32x4 cv;
#pragma unroll
  for (int r = 0; r < 4; ++r) cv[r] = c0[(size_t)(crow + r) * U_ + uw + fr];
  float bias_v[4];
#pragma unroll
  for (int g = 0; g < 4; ++g) bias_v[g] = bias[g * 1024 + uw + fr];

  const int ro  = (b >> 4) * 16;
  const int oc0 = (b & 15) * 32;
  const int os  = w >> 1;
  const int kq  = w & 1;
  const int orow = tid >> 4, ocl = tid & 15;
  const int hro = ro - m0;     // 0 or 16: out-row offset within staged Ast
  float bd_v[2];
#pragma unroll
  for (int j = 0; j < 2; ++j) bd_v[j] = bd[oc0 + j * 16 + ocl];

  const unsigned short* arow = &Ast[(size_t)(rt * 16 + fr) * APITCH + fk];
  const int sr = tid >> 3, sc = tid & 7;   // staging: row, chunk-lane

  // pre-stage x for t=0
  {
    const unsigned short* sx = &g_xbf[((size_t)(m0 + sr) * T_ + 0) * D_];
    int4v bx[8];
#pragma unroll
    for (int q = 0; q < 8; ++q) bx[q] = *(const int4v*)&sx[q * 64 + sc * 8];
#pragma unroll
    for (int q = 0; q < 8; ++q) *(int4v*)&Ast[(size_t)sr * APITCH + q * 64 + sc * 8] = bx[q];
  }

  // Iterations 0..T_-1: stage h_t, z-GEMM -> h_{t+1}, flag, out[t-1].
  // Iteration T_: stage h_T, out[T_-1] only.
  for (int t = 0; t <= T_; ++t) {
    // ---------- wait for m-group producers of slot t (distributed) ----------
    if (t > 0) {
      if (tid < 32) {
        unsigned int* fp = &g_flag[((b & ~31) + tid) * 32];
        while (__hip_atomic_load(fp, __ATOMIC_RELAXED, __HIP_MEMORY_SCOPE_AGENT) <
               (unsigned)t)
          __builtin_amdgcn_s_sleep(1);
      }
    }
    __syncthreads();   // wait settled; also fences prior iter's Ast readers

    // ---------- stage h_t (plain cached loads; line-granular, L2-shared) ----------
    {
      const unsigned short* hc = &g_hall[(size_t)t * (B_ * U_)];
      int4v bh[16];
#pragma unroll
      for (int q = 0; q < 16; ++q)
        bh[q] = *(const int4v*)&hc[(size_t)(m0 + sr) * U_ + q * 64 + sc * 8];
#pragma unroll
      for (int q = 0; q < 16; ++q)
        *(int4v*)&Ast[(size_t)sr * APITCH + 512 + q * 64 + sc * 8] = bh[q];
    }
    __syncthreads();

    if (t < T_) {
      // ---------- z = A @ W, 4 gates in-register, K=1536 ----------
      f32x4 az0 = {0.f, 0.f, 0.f, 0.f}, az1 = {0.f, 0.f, 0.f, 0.f};
      f32x4 az2 = {0.f, 0.f, 0.f, 0.f}, az3 = {0.f, 0.f, 0.f, 0.f};
#pragma unroll 4
      for (int kt = 0; kt < 48; ++kt) {
        const int ko = kt * 32;
        short8 a = *(const short8*)&arow[ko];
        az0 = __builtin_amdgcn_mfma_f32_16x16x32_bf16(a, *(const short8*)&wb[0][ko], az0, 0, 0, 0);
        az1 = __builtin_amdgcn_mfma_f32_16x16x32_bf16(a, *(const short8*)&wb[1][ko], az1, 0, 0, 0);
        az2 = __builtin_amdgcn_mfma_f32_16x16x32_bf16(a, *(const short8*)&wb[2][ko], az2, 0, 0, 0);
        az3 = __builtin_amdgcn_mfma_f32_16x16x32_bf16(a, *(const short8*)&wb[3][ko], az3, 0, 0, 0);
      }

      // ---------- gates + state update; h_{t+1} stores volatile (write-through) ----------
      {
        unsigned short* hn = &g_hall[(size_t)(t + 1) * (B_ * U_)];
#pragma unroll
        for (int r = 0; r < 4; ++r) {
          float zi = az0[r] + bias_v[0];
          float zf = az1[r] + bias_v[1];
          float zg = az2[r] + bias_v[2];
          float zo = az3[r] + bias_v[3];
          float ig = 1.f / (1.f + __expf(-zi));
          float fg = 1.f / (1.f + __expf(-zf));
          float og = 1.f / (1.f + __expf(-zo));
          float gg = tanhf(zg);
          cv[r] = fg * cv[r] + ig * gg;
          float hv = og * tanhf(cv[r]);
          *(volatile unsigned short*)&hn[(size_t)(crow + r) * U_ + uw + fr] = f2b(hv);
        }
      }
      __syncthreads();   // drains vmcnt(0): all waves' h stores are at the MALL

      // ---------- publish progress (relaxed: no cache maintenance) ----------
      if (tid == 0)
        __hip_atomic_store(&g_flag[b * 32], (unsigned)(t + 1), __ATOMIC_RELAXED,
                           __HIP_MEMORY_SCOPE_AGENT);

      // ---------- overlap: stage x for t+1 (hides under next flag wait) ----------
      if (t + 1 < T_) {
        const unsigned short* sx = &g_xbf[((size_t)(m0 + sr) * T_ + (t + 1)) * D_];
        int4v bx[8];
#pragma unroll
        for (int q = 0; q < 8; ++q) bx[q] = *(const int4v*)&sx[q * 64 + sc * 8];
#pragma unroll
        for (int q = 0; q < 8; ++q) *(int4v*)&Ast[(size_t)sr * APITCH + q * 64 + sc * 8] = bx[q];
      }
    }

    // ---------- out[t-1] = h_t @ Wd + bd, A read from LDS-staged h_t ----------
    if (t > 0) {
      f32x4 oa = {0.f, 0.f, 0.f, 0.f};
      const int kb = kq * 512;
      const unsigned short* ha = &Ast[(size_t)(hro + fr) * APITCH + 512 + kb + fk];
      const unsigned short* wa = &g_Wdt[(size_t)(oc0 + os * 16 + fr) * U_ + kb + fk];
#pragma unroll
      for (int s = 0; s < 16; ++s) {
        const int k = s * 32;
        oa = __builtin_amdgcn_mfma_f32_16x16x32_bf16(*(const short8*)&ha[k],
                                                     *(const short8*)&wa[k], oa, 0, 0, 0);
      }
#pragma unroll
      for (int r = 0; r < 4; ++r) po[w][rg * 4 + r][fr] = oa[r];
      __syncthreads();
#pragma unroll
      for (int j = 0; j < 2; ++j) {
        float v = po[j * 2][orow][ocl] + po[j * 2 + 1][orow][ocl] + bd_v[j];
        out[((size_t)(ro + orow) * T_ + (t - 1)) * O_ + oc0 + j * 16 + ocl] = v;
      }
    }
  }
}

extern "C" void kernel_launch(void* const* d_in, const int* in_sizes, int n_in,
                              void* d_out, int out_size, void* d_ws, size_t ws_size,
                              hipStream_t stream) {
  const float* x    = (const float*)d_in[0];
  const float* h0   = (const float*)d_in[1];
  const float* c0   = (const float*)d_in[2];
  const float* kern = (const float*)d_in[3];
  const float* rk   = (const float*)d_in[4];
  const float* bias = (const float*)d_in[5];
  const float* Wd   = (const float*)d_in[6];
  const float* bd   = (const float*)d_in[7];
  float* out = (float*)d_out;
  (void)in_sizes; (void)n_in; (void)d_ws; (void)ws_size; (void)out_size;

  prep_kernel<<<dim3(1024), dim3(256), 0, stream>>>(x, h0, kern, rk, Wd);
  lstm_kernel<<<dim3(NBLK), dim3(256), 0, stream>>>(c0, bias, bd, out);
}

// Round 2
// 2761.332 us; speedup vs baseline: 6.0229x; 5.2420x over previous
//
#include <hip/hip_runtime.h>
#include <hip/hip_bf16.h>

#define B_   128
#define T_   512
#define D_   512
#define U_   1024
#define O_   512
#define K_   1536      // D + U
#define G4U_ 4096
#define NBLK 256
#define APITCH 1544    // LDS A-row pitch in shorts (dword stride 772 ≡ 4 mod 32)

typedef __attribute__((ext_vector_type(8))) short short8;
typedef __attribute__((ext_vector_type(4))) float f32x4;
typedef __attribute__((ext_vector_type(4))) int int4v;

__device__ __align__(16) unsigned short g_xbf[(size_t)B_ * T_ * D_];   // x bf16 [b][t][d]
__device__ __align__(16) unsigned short g_Wt[(size_t)G4U_ * K_];       // W^T gate-grouped [cg][k]
__device__ __align__(16) unsigned short g_Wdt[(size_t)O_ * U_];        // Wd^T [o][u]
// h history: slot t holds h_t (slot 0 = h0). Unique slot per step -> cached consumer loads.
__device__ __align__(16) unsigned short g_hall[(size_t)(T_ + 1) * B_ * U_];
__device__ unsigned int g_flag[NBLK * 32];   // per-block progress, one 128B line each

__device__ __forceinline__ unsigned short f2b(float f) {
  unsigned u = __float_as_uint(f);
  u += 0x7fffu + ((u >> 16) & 1u);   // RNE
  return (unsigned short)(u >> 16);
}

__global__ void prep_kernel(const float* __restrict__ x, const float* __restrict__ h0,
                            const float* __restrict__ kern, const float* __restrict__ rkern,
                            const float* __restrict__ Wd) {
  size_t tid = (size_t)blockIdx.x * blockDim.x + threadIdx.x;
  size_t np  = (size_t)gridDim.x * blockDim.x;
  if (tid < NBLK * 32) g_flag[tid] = 0u;

  const size_t nx8 = (size_t)B_ * T_ * D_ / 8;
  const float4* xv = (const float4*)x;
  for (size_t i = tid; i < nx8; i += np) {
    float4 v0 = xv[2 * i], v1 = xv[2 * i + 1];
    unsigned short tmp[8];
    tmp[0] = f2b(v0.x); tmp[1] = f2b(v0.y); tmp[2] = f2b(v0.z); tmp[3] = f2b(v0.w);
    tmp[4] = f2b(v1.x); tmp[5] = f2b(v1.y); tmp[6] = f2b(v1.z); tmp[7] = f2b(v1.w);
    *(int4*)&g_xbf[i * 8] = *(const int4*)tmp;
  }

  // W layout (verified r1/r2): row cg = (u>>4)*64 + gate*16 + (u&15), k contiguous
  const size_t nw = (size_t)G4U_ * (K_ / 8);
  for (size_t i = tid; i < nw; i += np) {
    size_t cg = i / (K_ / 8);
    int kb = (int)(i % (K_ / 8)) * 8;
    int c = (int)(cg >> 6), g = (int)((cg >> 4) & 3), j = (int)(cg & 15);
    int n = g * 1024 + (c << 4) + j;
    unsigned short tmp[8];
#pragma unroll
    for (int q = 0; q < 8; ++q) {
      int k = kb + q;
      float v = (k < 512) ? kern[(size_t)k * G4U_ + n] : rkern[(size_t)(k - 512) * G4U_ + n];
      tmp[q] = f2b(v);
    }
    *(int4*)&g_Wt[cg * K_ + kb] = *(const int4*)tmp;
  }

  const size_t nd = (size_t)O_ * (U_ / 8);
  for (size_t i = tid; i < nd; i += np) {
    int o  = (int)(i >> 7);
    int ub = (int)(i & 127) * 8;
    unsigned short tmp[8];
#pragma unroll
    for (int q = 0; q < 8; ++q) tmp[q] = f2b(Wd[(size_t)(ub + q) * O_ + o]);
    *(int4*)&g_Wdt[(size_t)o * U_ + ub] = *(const int4*)tmp;
  }

  const size_t nh = (size_t)B_ * U_;
  for (size_t i = tid; i < nh; i += np) g_hall[i] = f2b(h0[i]);  // slot 0 = h0
}

// 256 persistent blocks x 256 threads, 1 block/CU (LDS-forced). Block b:
//   row-group mg = b>>6 (rows m0 = mg*32 .. +32), u-tile ug = b&63 (u0 = ug*16).
// ALL weights live in registers for the whole kernel:
//   z-weights: wave wq owns K-quarter [wq*384,+384): wz[12][4] short8 = 192 VGPR.
//   out-weights: wd[8] short8 = 32 VGPR (K-quarter of Wd for a 16x16 out tile).
// z inner loop is pure LDS+MFMA (no VMEM). Cross-wave K-reduce via padded LDS;
// each thread then owns 2 (row,u) elements with the full i,f,g,o quad in one f32x4.
__global__ __launch_bounds__(256, 1) void lstm_kernel(const float* __restrict__ c0,
                                                      const float* __restrict__ bias,
                                                      const float* __restrict__ bd,
                                                      float* __restrict__ out) {
  const int b    = blockIdx.x;
  const int tid  = threadIdx.x;
  const int wq   = tid >> 6;        // wave id = K-quarter
  const int lane = tid & 63;
  const int rg   = lane >> 4;
  const int fr   = lane & 15;

  const int mg = b >> 6;            // row group 0..3
  const int m0 = mg * 32;
  const int ug = b & 63;            // u-tile 0..63 (16 cols)
  const int u0 = ug * 16;

  __shared__ __align__(16) unsigned short Ast[32 * APITCH];   // 96.5 KB: A = [x | h]
  __shared__ f32x4 zpo[4][32][17];                            // 34 KB z partials (padded)
  __shared__ float po[4][16][20];                             // 5 KB out partials

  // ---------- one-time weight preload into registers ----------
  short8 wz[12][4];
#pragma unroll
  for (int kt = 0; kt < 12; ++kt)
#pragma unroll
    for (int g = 0; g < 4; ++g)
      wz[kt][g] = *(const short8*)&g_Wt[(size_t)(ug * 64 + g * 16 + fr) * K_ +
                                        wq * 384 + kt * 32 + rg * 8];

  const int oc0 = (ug >> 1) * 16;   // out col tile
  const int orh = (ug & 1) * 16;    // out row half within the 32 staged rows
  short8 wd[8];
#pragma unroll
  for (int kt = 0; kt < 8; ++kt)
    wd[kt] = *(const short8*)&g_Wdt[(size_t)(oc0 + fr) * U_ + wq * 256 + kt * 32 + rg * 8];

  // ---------- per-thread gate-element mapping: 2 els (erow, euu), (erow, euu+1) ----------
  const int erow = tid >> 3;
  const int euu  = (tid & 7) * 2;
  float cv[2];
  f32x4 bv[2];
#pragma unroll
  for (int j = 0; j < 2; ++j) {
    cv[j] = c0[(size_t)(m0 + erow) * U_ + u0 + euu + j];
    f32x4 tv;
#pragma unroll
    for (int g = 0; g < 4; ++g) tv[g] = bias[g * 1024 + u0 + euu + j];
    bv[j] = tv;
  }

  const int orow = tid >> 4, ocl = tid & 15;
  const float bd_v = bd[oc0 + ocl];

  const unsigned short* az0p = &Ast[(size_t)fr * APITCH + wq * 384 + rg * 8];
  const unsigned short* az1p = az0p + 16 * APITCH;
  const unsigned short* aop  = &Ast[(size_t)(orh + fr) * APITCH + 512 + wq * 256 + rg * 8];

  const int sr = tid >> 3, sc = tid & 7;   // staging: row, chunk-lane

  // pre-stage x for t=0
  {
    const unsigned short* sx = &g_xbf[((size_t)(m0 + sr) * T_ + 0) * D_];
    int4v bx[8];
#pragma unroll
    for (int q = 0; q < 8; ++q) bx[q] = *(const int4v*)&sx[q * 64 + sc * 8];
#pragma unroll
    for (int q = 0; q < 8; ++q) *(int4v*)&Ast[(size_t)sr * APITCH + q * 64 + sc * 8] = bx[q];
  }

  // Iterations 0..T_-1: stage h_t, z-GEMM -> h_{t+1}, flag, out[t-1].
  // Iteration T_: stage h_T, out[T_-1] only.
  for (int t = 0; t <= T_; ++t) {
    // ---------- wait for the 64 producers of my row-group's slot t ----------
    if (t > 0 && tid < 64) {
      unsigned int* fp = &g_flag[(mg * 64 + tid) * 32];
      while (__hip_atomic_load(fp, __ATOMIC_RELAXED, __HIP_MEMORY_SCOPE_AGENT) <
             (unsigned)t)
        __builtin_amdgcn_s_sleep(1);
    }
    __syncthreads();

    // ---------- stage h_t (plain cached; L2-shared by the 8 groupmates/XCD) ----------
    {
      const unsigned short* hc = &g_hall[(size_t)t * (B_ * U_)];
      int4v bh[16];
#pragma unroll
      for (int q = 0; q < 16; ++q)
        bh[q] = *(const int4v*)&hc[(size_t)(m0 + sr) * U_ + q * 64 + sc * 8];
#pragma unroll
      for (int q = 0; q < 16; ++q)
        *(int4v*)&Ast[(size_t)sr * APITCH + 512 + q * 64 + sc * 8] = bh[q];
    }
    __syncthreads();

    if (t < T_) {
      // ---------- z partial: pure LDS+MFMA, weights from registers ----------
      f32x4 acc[2][4];
#pragma unroll
      for (int rt = 0; rt < 2; ++rt)
#pragma unroll
        for (int g = 0; g < 4; ++g) acc[rt][g] = (f32x4){0.f, 0.f, 0.f, 0.f};
#pragma unroll
      for (int kt = 0; kt < 12; ++kt) {
        short8 a0 = *(const short8*)&az0p[kt * 32];
        short8 a1 = *(const short8*)&az1p[kt * 32];
#pragma unroll
        for (int g = 0; g < 4; ++g) {
          acc[0][g] = __builtin_amdgcn_mfma_f32_16x16x32_bf16(a0, wz[kt][g], acc[0][g], 0, 0, 0);
          acc[1][g] = __builtin_amdgcn_mfma_f32_16x16x32_bf16(a1, wz[kt][g], acc[1][g], 0, 0, 0);
        }
      }
      // partials -> LDS: one f32x4 (i,f,g,o) per (row, u) element
#pragma unroll
      for (int rt = 0; rt < 2; ++rt)
#pragma unroll
        for (int r = 0; r < 4; ++r) {
          f32x4 v = {acc[rt][0][r], acc[rt][1][r], acc[rt][2][r], acc[rt][3][r]};
          zpo[wq][rt * 16 + rg * 4 + r][fr] = v;
        }
      __syncthreads();

      // ---------- K-reduce + gates + state update; coalesced packed h store ----------
      {
        unsigned short* hn = &g_hall[(size_t)(t + 1) * (B_ * U_)];
        float hv[2];
#pragma unroll
        for (int j = 0; j < 2; ++j) {
          f32x4 z = zpo[0][erow][euu + j] + zpo[1][erow][euu + j] +
                    zpo[2][erow][euu + j] + zpo[3][erow][euu + j];
          z += bv[j];
          float ig = 1.f / (1.f + __expf(-z[0]));
          float fg = 1.f / (1.f + __expf(-z[1]));
          float gg = tanhf(z[2]);
          float og = 1.f / (1.f + __expf(-z[3]));
          cv[j] = fg * cv[j] + ig * gg;
          hv[j] = og * tanhf(cv[j]);
        }
        unsigned int pk = (unsigned)f2b(hv[0]) | ((unsigned)f2b(hv[1]) << 16);
        *(volatile unsigned int*)&hn[(size_t)(m0 + erow) * U_ + u0 + euu] = pk;
      }
      __syncthreads();   // drains vmcnt(0): all h stores are at the MALL

      // ---------- publish progress ----------
      if (tid == 0)
        __hip_atomic_store(&g_flag[b * 32], (unsigned)(t + 1), __ATOMIC_RELAXED,
                           __HIP_MEMORY_SCOPE_AGENT);

      // ---------- overlap: stage x for t+1 ----------
      if (t + 1 < T_) {
        const unsigned short* sx = &g_xbf[((size_t)(m0 + sr) * T_ + (t + 1)) * D_];
        int4v bx[8];
#pragma unroll
        for (int q = 0; q < 8; ++q) bx[q] = *(const int4v*)&sx[q * 64 + sc * 8];
#pragma unroll
        for (int q = 0; q < 8; ++q) *(int4v*)&Ast[(size_t)sr * APITCH + q * 64 + sc * 8] = bx[q];
      }
    }

    // ---------- out[t-1] = h_t @ Wd + bd (16x16 tile, K split across waves) ----------
    if (t > 0) {
      f32x4 oa = {0.f, 0.f, 0.f, 0.f};
#pragma unroll
      for (int kt = 0; kt < 8; ++kt)
        oa = __builtin_amdgcn_mfma_f32_16x16x32_bf16(*(const short8*)&aop[kt * 32],
                                                     wd[kt], oa, 0, 0, 0);
#pragma unroll
      for (int r = 0; r < 4; ++r) po[wq][rg * 4 + r][fr] = oa[r];
      __syncthreads();
      float v = po[0][orow][ocl] + po[1][orow][ocl] + po[2][orow][ocl] +
                po[3][orow][ocl] + bd_v;
      out[((size_t)(m0 + orh + orow) * T_ + (t - 1)) * O_ + oc0 + ocl] = v;
    }
  }
}

extern "C" void kernel_launch(void* const* d_in, const int* in_sizes, int n_in,
                              void* d_out, int out_size, void* d_ws, size_t ws_size,
                              hipStream_t stream) {
  const float* x    = (const float*)d_in[0];
  const float* h0   = (const float*)d_in[1];
  const float* c0   = (const float*)d_in[2];
  const float* kern = (const float*)d_in[3];
  const float* rk   = (const float*)d_in[4];
  const float* bias = (const float*)d_in[5];
  const float* Wd   = (const float*)d_in[6];
  const float* bd   = (const float*)d_in[7];
  float* out = (float*)d_out;
  (void)in_sizes; (void)n_in; (void)d_ws; (void)ws_size; (void)out_size;

  prep_kernel<<<dim3(1024), dim3(256), 0, stream>>>(x, h0, kern, rk, Wd);
  lstm_kernel<<<dim3(NBLK), dim3(256), 0, stream>>>(c0, bias, bd, out);
}